// Round 1
// baseline (1893.789 us; speedup 1.0000x reference)
//
#include <hip/hip_runtime.h>
#include <stdint.h>

// LSTM forward, MI355X. Sizes fixed by the problem:
//   H=128, I=270, C=3, B=1024, T=270, NU=4*H=512, W rows are 398 (=[h|x] cols).
//
// Plan:
//  K1 xp_gemm    : xp[t,b,u] = sum_i x[b,t,i]*W_g[j][128+i] + bias_g[j]  (bf16 out, MFMA)
//                  computed per time-chunk into d_ws (1 MB per t).
//  K2 lstm_scan  : 256 blocks x 4 batch rows, iterate t locally. Recurrent GEMM
//                  via mfma_f32_16x16x32_bf16, Wh frags register-resident,
//                  h exchanged via double-buffered LDS (1 barrier/step).
//                  c stays fp32 in registers; persists across chunks via d_ws.
//                  h persists via out0 (it's an output anyway).
//  K3 logits_softmax: y = softmax(h @ Wy^T + by), fp32, trivially parallel.

typedef __attribute__((ext_vector_type(8))) short short8;   // 8 bf16 = 4 VGPR (MFMA A/B frag)
typedef __attribute__((ext_vector_type(4))) float f32x4;    // MFMA C/D frag
typedef __attribute__((ext_vector_type(2))) float f32x2;

__device__ inline unsigned short f2bf(float f) {            // fp32 -> bf16, RNE
    unsigned u = __float_as_uint(f);
    return (unsigned short)((u + 0x7FFFu + ((u >> 16) & 1u)) >> 16);
}
__device__ inline float bf2f(unsigned short s) {
    return __uint_as_float(((unsigned)s) << 16);
}
__device__ inline float sigm_f(float x) {
    x = fminf(fmaxf(x, -30.f), 30.f);
    return 1.f / (1.f + __expf(-x));
}
__device__ inline float tanh_f(float x) {
    x = fminf(fmaxf(x, -15.f), 15.f);
    float e = __expf(-2.f * x);
    return (1.f - e) / (1.f + e);
}

#define KPAD 288   // K=270 zero-padded to 9 MFMA k-frags
#define ASTR 296   // LDS row stride (bf16 elems): 296*2B=592B -> ~2-way banks on frag reads

// ---------------- K1: input-projection GEMM (chunk of Tcur steps) ----------------
// Block tile: 128 rows (M) x 128 units (N), full K. A (x) staged fp32->bf16 in LDS;
// B (Wx) fragments preloaded from global (L2-hot, shared by all blocks) into regs.
// 512 thr = 8 waves as 2(m) x 4(n); per wave: 4 m-tiles x 2 n-tiles x 9 k-frags.
__global__ __launch_bounds__(512) void xp_gemm(
    const float* __restrict__ x,
    const float* __restrict__ Wf, const float* __restrict__ Wi,
    const float* __restrict__ Wc, const float* __restrict__ Wo,
    const float* __restrict__ bfp, const float* __restrict__ bip,
    const float* __restrict__ bcp, const float* __restrict__ bop,
    unsigned short* __restrict__ xpc, int t0, int Tcur)
{
    __shared__ unsigned short A_lds[128 * ASTR];
    const int tid  = threadIdx.x;
    const int blkM = blockIdx.x;      // [0, Tcur*8)
    const int blkN = blockIdx.y;      // [0, 4)

    // stage A tile (128 rows of x, k zero-padded to 288)
    {
        const int base_row = blkM * 128;
        for (int idx = tid; idx < 128 * KPAD; idx += 512) {
            int r_loc = idx / KPAD;
            int k     = idx - r_loc * KPAD;
            int r_glob = base_row + r_loc;
            int tt = r_glob >> 10;          // chunk-local t
            int b  = r_glob & 1023;
            float v = 0.f;
            if (k < 270) v = x[(size_t)b * (270 * 270) + (size_t)(t0 + tt) * 270 + k];
            A_lds[r_loc * ASTR + k] = f2bf(v);
        }
    }

    const int l    = tid & 63;
    const int w    = tid >> 6;
    const int wave_m = w >> 2;        // 0..1
    const int wave_n = w & 3;         // 0..3
    const int l16  = l & 15;
    const int lq   = l >> 4;          // 0..3

    // B frags (Wx) + bias, straight from global. B[k][n] = Wx[u=n][i=k] = W_g[j][128+i]
    short8 bfrag[2][9];
    float  bias_v[2];
    #pragma unroll
    for (int nt = 0; nt < 2; ++nt) {
        int ubase = blkN * 128 + wave_n * 32 + nt * 16;   // 16-aligned -> single gate
        int g = ubase >> 7;
        const float* Wg = (g == 0) ? Wf : (g == 1) ? Wi : (g == 2) ? Wc : Wo;
        const float* bg = (g == 0) ? bfp : (g == 1) ? bip : (g == 2) ? bcp : bop;
        int j = (ubase & 127) + l16;
        const float* row = Wg + (size_t)j * 398 + 128;    // +128: the x-part of [h|x]
        bias_v[nt] = bg[(ubase & 127) + l16];
        #pragma unroll
        for (int kf = 0; kf < 9; ++kf) {
            int i0 = kf * 32 + lq * 8;
            short8 fr;
            #pragma unroll
            for (int p = 0; p < 4; ++p) {
                int ii = i0 + p * 2;
                float a = 0.f, b2 = 0.f;
                if (ii < 270) { f32x2 v = *(const f32x2*)(row + ii); a = v.x; b2 = v.y; }
                fr[p * 2]     = (short)f2bf(a);
                fr[p * 2 + 1] = (short)f2bf(b2);
            }
            bfrag[nt][kf] = fr;
        }
    }
    __syncthreads();

    f32x4 acc[4][2];
    #pragma unroll
    for (int mt = 0; mt < 4; ++mt)
        #pragma unroll
        for (int nt = 0; nt < 2; ++nt)
            acc[mt][nt] = (f32x4){bias_v[nt], bias_v[nt], bias_v[nt], bias_v[nt]};

    #pragma unroll
    for (int kf = 0; kf < 9; ++kf) {
        short8 afr[4];
        #pragma unroll
        for (int mt = 0; mt < 4; ++mt) {
            int row = wave_m * 64 + mt * 16 + l16;
            afr[mt] = *(const short8*)(&A_lds[row * ASTR + kf * 32 + lq * 8]);
        }
        #pragma unroll
        for (int mt = 0; mt < 4; ++mt)
            #pragma unroll
            for (int nt = 0; nt < 2; ++nt)
                acc[mt][nt] = __builtin_amdgcn_mfma_f32_16x16x32_bf16(
                    afr[mt], bfrag[nt][kf], acc[mt][nt], 0, 0, 0);
    }

    // store xp as bf16: C layout col=lane&15, row=(lane>>4)*4+reg (m89-verified)
    #pragma unroll
    for (int mt = 0; mt < 4; ++mt)
        #pragma unroll
        for (int nt = 0; nt < 2; ++nt) {
            int u = blkN * 128 + wave_n * 32 + nt * 16 + l16;
            #pragma unroll
            for (int q = 0; q < 4; ++q) {
                int r_glob = blkM * 128 + wave_m * 64 + mt * 16 + lq * 4 + q;
                xpc[(size_t)r_glob * 512 + u] = f2bf(acc[mt][nt][q]);
            }
        }
}

// ---------------- K2: the sequential scan ----------------
// 256 blocks x 512 thr (8 waves). Block owns 4 batch rows. Wave w owns unit slice
// jcol = w*16 + (lane&15) for ALL 4 gates (so gate mixing is lane-local).
// Recurrent GEMM M=16 (4 real rows), N=512, K=128 via 16 MFMAs/wave/step.
__global__ __launch_bounds__(512) void lstm_scan(
    const unsigned short* __restrict__ xpc,
    float* __restrict__ c_state,
    float* __restrict__ out0,
    const float* __restrict__ Wf, const float* __restrict__ Wi,
    const float* __restrict__ Wc, const float* __restrict__ Wo,
    int t0, int t1)
{
    // h staging: [buf][m=16][k=128] bf16, XOR-swizzled byte^=((m&7)<<4) to break
    // the 256B-stride bank conflict on the A-frag ds_read_b128.
    __shared__ unsigned short h_lds[2][16 * 128];
    const int tid  = threadIdx.x;
    const int l    = tid & 63;
    const int w    = tid >> 6;
    const int l16  = l & 15;
    const int lq   = l >> 4;
    const int b0   = blockIdx.x * 4;
    const int jcol = w * 16 + l16;          // unit index within gate [0,128)

    // Wh frags, register-resident for the whole scan.
    // B[k][n] = Wh[u0+n][k] = W_g[jrow][k], jrow = w*16 + (l&15), k = kf*32 + lq*8 + jj
    short8 whf[4][4];
    {
        const float* Ws[4] = {Wf, Wi, Wc, Wo};
        #pragma unroll
        for (int g = 0; g < 4; ++g) {
            const float* row = Ws[g] + (size_t)jcol * 398;   // cols [0,128) = h-part
            #pragma unroll
            for (int kf = 0; kf < 4; ++kf) {
                int k0 = kf * 32 + lq * 8;
                short8 fr;
                #pragma unroll
                for (int p = 0; p < 4; ++p) {
                    f32x2 v = *(const f32x2*)(row + k0 + p * 2);
                    fr[p * 2]     = (short)f2bf(v.x);
                    fr[p * 2 + 1] = (short)f2bf(v.y);
                }
                whf[g][kf] = fr;
            }
        }
    }

    // zero both h buffers (rows 4..15 must stay zero forever)
    {
        unsigned short* hp = &h_lds[0][0];
        for (int idx = tid; idx < 2 * 16 * 128; idx += 512) hp[idx] = 0;
    }
    __syncthreads();

    int   cur = 0;
    float c_reg[4] = {0.f, 0.f, 0.f, 0.f};
    if (t0 != 0) {
        if (l < 16) {
            #pragma unroll
            for (int r = 0; r < 4; ++r)
                c_reg[r] = c_state[(size_t)(b0 + r) * 128 + jcol];
        }
        // h comes back from out0 (it was written there at t0-1)
        {
            int r = tid >> 7;        // 0..3
            int k = tid & 127;
            float hv = out0[(size_t)(b0 + r) * (270 * 128) + (size_t)(t0 - 1) * 128 + k];
            int off = ((r * 128 + k) * 2) ^ ((r & 7) << 4);
            *(unsigned short*)((char*)(&h_lds[cur][0]) + off) = f2bf(hv);
        }
        __syncthreads();
    }

    // xp prefetch (lanes 0..15 hold rows via regs). Imm offsets (r*512+g*128)*2 < 4096.
    unsigned short P[16];
    const unsigned short* xp_t = xpc + (size_t)b0 * 512 + jcol;  // tt = 0
    if (l < 16) {
        #pragma unroll
        for (int g = 0; g < 4; ++g)
            #pragma unroll
            for (int r = 0; r < 4; ++r)
                P[g * 4 + r] = xp_t[r * 512 + g * 128];
    }

    for (int t = t0; t < t1; ++t) {
        // A frags from h_lds[cur]: A[m][k], m=l&15 (rows 4..15 are zero)
        short8 afr[4];
        #pragma unroll
        for (int kf = 0; kf < 4; ++kf) {
            int k0 = kf * 32 + lq * 8;
            int off = ((l16 * 128 + k0) * 2) ^ ((l16 & 7) << 4);
            afr[kf] = *(const short8*)((const char*)(&h_lds[cur][0]) + off);
        }

        // acc init = xp (+bias, folded in K1). Only lanes<16 carry real rows.
        f32x4 acc[4];
        #pragma unroll
        for (int g = 0; g < 4; ++g) {
            if (l < 16)
                acc[g] = (f32x4){bf2f(P[g * 4 + 0]), bf2f(P[g * 4 + 1]),
                                 bf2f(P[g * 4 + 2]), bf2f(P[g * 4 + 3])};
            else
                acc[g] = (f32x4){0.f, 0.f, 0.f, 0.f};
        }

        // prefetch next step's xp (hides L3/HBM latency under gates)
        if (t + 1 < t1) {
            xp_t += 1024 * 512;
            if (l < 16) {
                #pragma unroll
                for (int g = 0; g < 4; ++g)
                    #pragma unroll
                    for (int r = 0; r < 4; ++r)
                        P[g * 4 + r] = xp_t[r * 512 + g * 128];
            }
        }

        #pragma unroll
        for (int kf = 0; kf < 4; ++kf)
            #pragma unroll
            for (int g = 0; g < 4; ++g)
                acc[g] = __builtin_amdgcn_mfma_f32_16x16x32_bf16(
                    afr[kf], whf[g][kf], acc[g], 0, 0, 0);

        // gates (divergent: lanes 0..15 hold rows 0..3 in regs 0..3)
        if (l < 16) {
            #pragma unroll
            for (int r = 0; r < 4; ++r) {
                float pf = acc[0][r], pi = acc[1][r], pc = acc[2][r], po = acc[3][r];
                float fg = sigm_f(pf);
                float ig = sigm_f(pi);
                float gg = tanh_f(pc);
                float og = sigm_f(po);
                float cn = fg * c_reg[r] + ig * gg;
                c_reg[r] = cn;
                float hv = og * tanh_f(cn);
                out0[(size_t)(b0 + r) * (270 * 128) + (size_t)t * 128 + jcol] = hv;
                int off = ((r * 128 + jcol) * 2) ^ ((r & 7) << 4);
                *(unsigned short*)((char*)(&h_lds[cur ^ 1][0]) + off) = f2bf(hv);
            }
        }
        __syncthreads();
        cur ^= 1;
    }

    if (l < 16) {
        #pragma unroll
        for (int r = 0; r < 4; ++r)
            c_state[(size_t)(b0 + r) * 128 + jcol] = c_reg[r];
    }
}

// ---------------- K3: logits + softmax ----------------
// Block: 256 thr, 64 (b,t) pairs. h staged to LDS (padded stride 132), thread =
// (pair, class); softmax across the 4-lane group via shfl_xor.
__global__ __launch_bounds__(256) void logits_softmax(
    const float* __restrict__ h_all, const float* __restrict__ Wy,
    const float* __restrict__ by, float* __restrict__ out1)
{
    __shared__ float h_s[64 * 132];
    __shared__ float wy_s[3 * 128];
    const int tid = threadIdx.x;
    const size_t p0 = (size_t)blockIdx.x * 64;

    for (int v = tid; v < 2048; v += 256) {
        int q = v >> 5, kk = v & 31;
        f32x4 g = *(const f32x4*)(h_all + p0 * 128 + (size_t)v * 4);
        *(f32x4*)(&h_s[q * 132 + kk * 4]) = g;
    }
    for (int v = tid; v < 384; v += 256) wy_s[v] = Wy[v];
    __syncthreads();

    int q  = tid >> 2, cc = tid & 3;
    int ccw = cc < 3 ? cc : 2;            // lane 3: dummy reads, masked later
    float L = 0.f;
    #pragma unroll
    for (int k4 = 0; k4 < 32; ++k4) {
        f32x4 hv = *(const f32x4*)(&h_s[q * 132 + k4 * 4]);
        f32x4 wv = *(const f32x4*)(&wy_s[ccw * 128 + k4 * 4]);
        L += hv.x * wv.x + hv.y * wv.y + hv.z * wv.z + hv.w * wv.w;
    }
    L += by[ccw];
    if (cc == 3) L = -1e30f;
    float m = fmaxf(L, __shfl_xor(L, 1));
    m = fmaxf(m, __shfl_xor(m, 2));
    float e = (cc < 3) ? __expf(L - m) : 0.f;
    float s = e + __shfl_xor(e, 1);
    s = s + __shfl_xor(s, 2);
    if (cc < 3) out1[(p0 + q) * 3 + cc] = e / s;
}

// ---------------- host ----------------
extern "C" void kernel_launch(void* const* d_in, const int* in_sizes, int n_in,
                              void* d_out, int out_size, void* d_ws, size_t ws_size,
                              hipStream_t stream) {
    (void)in_sizes; (void)n_in; (void)out_size;
    const float* x   = (const float*)d_in[0];
    const float* Wf  = (const float*)d_in[1];
    const float* Wi  = (const float*)d_in[2];
    const float* Wc  = (const float*)d_in[3];
    const float* Wo  = (const float*)d_in[4];
    const float* Wy  = (const float*)d_in[5];
    const float* bfp = (const float*)d_in[6];
    const float* bip = (const float*)d_in[7];
    const float* bcp = (const float*)d_in[8];
    const float* bop = (const float*)d_in[9];
    const float* byp = (const float*)d_in[10];

    float* out0 = (float*)d_out;                              // [B,T,H]
    float* out1 = out0 + (size_t)1024 * 270 * 128;            // [B,T,3]

    // ws layout: xpc bf16 chunk buffer (1 MB per timestep) + c_state (512 KB)
    long tc = 90;                                             // 270 = 3 x 90
    {
        size_t need = (size_t)tc * 1048576 + 524288;
        if (need > ws_size) {
            long avail = (long)ws_size - 524288;
            tc = avail > 0 ? avail / 1048576 : 1;
            if (tc < 1) tc = 1;
        }
    }
    unsigned short* xpc = (unsigned short*)d_ws;
    float* c_state = (float*)((char*)d_ws + (size_t)tc * 1048576);

    for (int t0 = 0; t0 < 270; t0 += (int)tc) {
        int Tcur = (270 - t0) < (int)tc ? (270 - t0) : (int)tc;
        dim3 gA(Tcur * 8, 4);
        xp_gemm<<<gA, 512, 0, stream>>>(x, Wf, Wi, Wc, Wo, bfp, bip, bcp, bop,
                                        xpc, t0, Tcur);
        lstm_scan<<<256, 512, 0, stream>>>(xpc, c_state, out0, Wf, Wi, Wc, Wo,
                                           t0, t0 + Tcur);
    }
    logits_softmax<<<4320, 256, 0, stream>>>(out0, Wy, byp, out1);
}

// Round 2
// 641.437 us; speedup vs baseline: 2.9524x; 2.9524x over previous
//
#include <hip/hip_runtime.h>
#include <stdint.h>

// LSTM forward, MI355X. H=128, I=270, C=3, B=1024, T=270, NU=512, W rows 398.
// Pipeline per chunk of Tcur steps:
//   pack_w (once): Wx->bf16 [512][288] padded, Wh->bf16 [512][128], bias->bpk[512]
//   xconv : x fp32 -> xbf bf16 [Tcur*1024][288], 16B slots XOR-pre-swizzled per row
//   xp_gemm: xp[t,b,u] = x@Wx^T + b via MFMA, global_load_lds staging, 3-deep pipe
//   lstm_scan: 256 blocks x 4 batch rows, recurrent MFMA, full-wave gates
//   logits_softmax at the end.

typedef __attribute__((ext_vector_type(8))) short short8;
typedef __attribute__((ext_vector_type(4))) float f32x4;
typedef __attribute__((ext_vector_type(2))) float f32x2;
typedef unsigned short ush;

__device__ __forceinline__ ush f2bf(float f) {
    unsigned u = __float_as_uint(f);
    return (ush)((u + 0x7FFFu + ((u >> 16) & 1u)) >> 16);
}
__device__ __forceinline__ float bf2f(ush s) { return __uint_as_float(((unsigned)s) << 16); }
__device__ __forceinline__ float sigm_f(float x) {
    x = fminf(fmaxf(x, -30.f), 30.f);
    return 1.f / (1.f + __expf(-x));
}
__device__ __forceinline__ float tanh_f(float x) {
    x = fminf(fmaxf(x, -15.f), 15.f);
    float e = __expf(-2.f * x);
    return (1.f - e) / (1.f + e);
}
__device__ __forceinline__ void gl_lds16(const void* g, void* l) {
    __builtin_amdgcn_global_load_lds(
        (const __attribute__((address_space(1))) unsigned int*)g,
        (__attribute__((address_space(3))) unsigned int*)l, 16, 0, 0);
}

// ---------------- pack_w: one-time weight/bias packing ----------------
__global__ __launch_bounds__(256) void pack_w(
    const float* __restrict__ Wf, const float* __restrict__ Wi,
    const float* __restrict__ Wc, const float* __restrict__ Wo,
    const float* __restrict__ bf_, const float* __restrict__ bi_,
    const float* __restrict__ bc_, const float* __restrict__ bo_,
    ush* __restrict__ Wxp, ush* __restrict__ Whp, float* __restrict__ bpk)
{
    int idx = blockIdx.x * 256 + threadIdx.x;
    if (idx < 512 * 288) {
        int u = idx / 288, i = idx - u * 288;
        int g = u >> 7, j = u & 127;
        const float* Wg = (g == 0) ? Wf : (g == 1) ? Wi : (g == 2) ? Wc : Wo;
        float v = (i < 270) ? Wg[(size_t)j * 398 + 128 + i] : 0.f;
        Wxp[idx] = f2bf(v);
    }
    if (idx < 512 * 128) {
        int u = idx >> 7, k = idx & 127;
        int g = u >> 7, j = u & 127;
        const float* Wg = (g == 0) ? Wf : (g == 1) ? Wi : (g == 2) ? Wc : Wo;
        Whp[idx] = f2bf(Wg[(size_t)j * 398 + k]);
    }
    if (idx < 512) {
        int g = idx >> 7, j = idx & 127;
        const float* bg = (g == 0) ? bf_ : (g == 1) ? bi_ : (g == 2) ? bc_ : bo_;
        bpk[idx] = bg[j];
    }
}

// ---------------- xconv: x fp32 -> bf16, padded to 288, slot-preswizzled ----------------
// Row r (= tt*1024+b): 36 chunks of 16B (9 K-groups x 4 slots). Physical slot s holds
// logical slot (s&3)^((r>>1)&3) so GEMM's LDS frag reads are ~conflict-free.
__global__ __launch_bounds__(576) void xconv(
    const float* __restrict__ x, ush* __restrict__ xbf, int t0, int rows)
{
    int tid = threadIdx.x;
    int r = blockIdx.x * 16 + tid / 36;
    int s = tid % 36;
    if (r >= rows) return;
    int swz = (r >> 1) & 3;
    int i0 = (s >> 2) * 32 + (((s & 3) ^ swz)) * 8;
    int tt = r >> 10, b = r & 1023;
    const float* src = x + ((size_t)b * 270 + (size_t)(t0 + tt)) * 270 + i0;
    short8 o;
    if (i0 + 8 <= 270) {
        #pragma unroll
        for (int p = 0; p < 4; ++p) {
            f32x2 v = *(const f32x2*)(src + p * 2);   // 8B aligned (row base 1080B, i0%8==0)
            o[p * 2]     = (short)f2bf(v.x);
            o[p * 2 + 1] = (short)f2bf(v.y);
        }
    } else {
        #pragma unroll
        for (int j = 0; j < 8; ++j)
            o[j] = (i0 + j < 270) ? (short)f2bf(src[j]) : (short)0;
    }
    *(short8*)(xbf + (size_t)r * 288 + s * 8) = o;
}

// ---------------- xp_gemm: [rows x 288] @ [288 x 512] -> bf16 xpc ----------------
// Block: 128x128 tile, 8 waves (2m x 4n), 3 M-tiles per block, K=288 in 9 steps.
// A staged via global_load_lds into 3 rotating 8KB buffers; counted vmcnt(1).
__global__ __launch_bounds__(512) void xp_gemm(
    const ush* __restrict__ xbf, const ush* __restrict__ Wxp,
    const float* __restrict__ bpk, ush* __restrict__ xpc)
{
    __shared__ ush A_buf[3][128 * 32];
    const int tid = threadIdx.x;
    const int l = tid & 63, w = tid >> 6;
    const int l16 = l & 15, lq = l >> 4;
    const int wave_m = w >> 2, wave_n = w & 3;
    const int blkN = blockIdx.y;
    const int tile0 = blockIdx.x * 3;

    // B fragments (register-resident, L2-hot clean b128 loads) + bias
    short8 bfrag[2][9];
    float bias_v[2];
    int ucol[2];
    #pragma unroll
    for (int nt = 0; nt < 2; ++nt) {
        int u = blkN * 128 + wave_n * 32 + nt * 16 + l16;
        ucol[nt] = u;
        bias_v[nt] = bpk[u];
        const ush* bw = Wxp + (size_t)u * 288 + lq * 8;
        #pragma unroll
        for (int ks = 0; ks < 9; ++ks)
            bfrag[nt][ks] = *(const short8*)(bw + ks * 32);
    }

    const int r_in_tile = w * 16 + (l >> 2);
    const ush* src_base = xbf + (size_t)(tile0 * 128 + r_in_tile) * 288 + (l & 3) * 8;
    const int swzr = (l16 >> 1) & 3;

    f32x4 acc[4][2];
    #pragma unroll
    for (int mt = 0; mt < 4; ++mt)
        #pragma unroll
        for (int nt = 0; nt < 2; ++nt)
            acc[mt][nt] = (f32x4){bias_v[nt], bias_v[nt], bias_v[nt], bias_v[nt]};

    // prologue: stage steps 0,1
    gl_lds16(src_base, &A_buf[0][w * 512]);
    gl_lds16(src_base + 32, &A_buf[1][w * 512]);
    asm volatile("s_waitcnt vmcnt(1)" ::: "memory");
    __syncthreads();

    #pragma unroll
    for (int mi = 0; mi < 3; ++mi) {
        #pragma unroll
        for (int ks = 0; ks < 9; ++ks) {
            const int step = mi * 9 + ks;
            // stage step+2 early (slot (step+2)%3 was freed by the step-1 barrier)
            if (step + 2 < 27) {
                const int s2 = step + 2;
                const int mi2 = s2 / 9, ks2 = s2 - mi2 * 9;
                gl_lds16(src_base + (size_t)mi2 * (128 * 288) + ks2 * 32,
                         &A_buf[s2 % 3][w * 512]);
            }
            // A frags from buffer step%3 (swizzled slot -> 2-way banks, free)
            short8 afr[4];
            #pragma unroll
            for (int mt = 0; mt < 4; ++mt) {
                int boff = (wave_m * 64 + mt * 16 + l16) * 64 + ((lq ^ swzr) * 16);
                afr[mt] = *(const short8*)((const char*)(&A_buf[step % 3][0]) + boff);
            }
            #pragma unroll
            for (int mt = 0; mt < 4; ++mt)
                #pragma unroll
                for (int nt = 0; nt < 2; ++nt)
                    acc[mt][nt] = __builtin_amdgcn_mfma_f32_16x16x32_bf16(
                        afr[mt], bfrag[nt][ks], acc[mt][nt], 0, 0, 0);
            if (ks == 8) {
                #pragma unroll
                for (int mt = 0; mt < 4; ++mt)
                    #pragma unroll
                    for (int nt = 0; nt < 2; ++nt) {
                        size_t rg = (size_t)(tile0 + mi) * 128 + wave_m * 64 + mt * 16 + lq * 4;
                        #pragma unroll
                        for (int q = 0; q < 4; ++q)
                            xpc[(rg + q) * 512 + ucol[nt]] = f2bf(acc[mt][nt][q]);
                        acc[mt][nt] = (f32x4){bias_v[nt], bias_v[nt], bias_v[nt], bias_v[nt]};
                    }
                asm volatile("s_waitcnt vmcnt(0)" ::: "memory");
            } else {
                asm volatile("s_waitcnt vmcnt(1)" ::: "memory");
            }
            __syncthreads();
        }
    }
}

// ---------------- lstm_scan: sequential recurrence ----------------
// 256 blocks x 512 thr. Block owns 4 batch rows; lane owns (row=lq, unit jcol).
// Recurrent GEMM M=16(4 real) x N=512 x K=128 via 16 MFMAs/wave; h via LDS dbuf.
__global__ __launch_bounds__(512) void lstm_scan(
    const ush* __restrict__ xpc, const ush* __restrict__ Whp,
    float* __restrict__ c_state, float* __restrict__ out0, int t0, int t1)
{
    __shared__ ush h_lds[2][16 * 128];
    const int tid = threadIdx.x;
    const int l = tid & 63, w = tid >> 6;
    const int l16 = l & 15, lq = l >> 4;
    const int b0 = blockIdx.x * 4;
    const int jcol = w * 16 + l16;

    // Wh frags register-resident (from packed bf16)
    short8 whf[4][4];
    #pragma unroll
    for (int g = 0; g < 4; ++g) {
        const ush* bw = Whp + ((size_t)(g * 128 + jcol)) * 128 + lq * 8;
        #pragma unroll
        for (int kf = 0; kf < 4; ++kf)
            whf[g][kf] = *(const short8*)(bw + kf * 32);
    }

    {   // zero both h buffers (rows 4..15 stay zero forever)
        ush* hp = &h_lds[0][0];
        for (int idx = tid; idx < 2 * 16 * 128; idx += 512) hp[idx] = 0;
    }
    __syncthreads();

    int cur = 0;
    float c1 = 0.f;
    if (t0 != 0) {
        c1 = c_state[(size_t)(b0 + lq) * 128 + jcol];
        int r = tid >> 7, k = tid & 127;
        float hv = out0[(size_t)(b0 + r) * (270 * 128) + (size_t)(t0 - 1) * 128 + k];
        int off = ((r * 128 + k) * 2) ^ ((r & 7) << 4);
        *(ush*)((char*)(&h_lds[0][0]) + off) = f2bf(hv);
        __syncthreads();
    }

    // xp prefetch: 4 loads, full-wave (lane owns (lq, jcol))
    const ush* xp_base = xpc + ((size_t)(b0 + lq)) * 512 + jcol;
    ush P[4];
    {
        #pragma unroll
        for (int g = 0; g < 4; ++g) P[g] = xp_base[g * 128];
    }

    for (int t = t0; t < t1; ++t) {
        short8 afr[4];
        #pragma unroll
        for (int kf = 0; kf < 4; ++kf) {
            int off = ((l16 * 128 + kf * 32 + lq * 8) * 2) ^ ((l16 & 7) << 4);
            afr[kf] = *(const short8*)((const char*)(&h_lds[cur][0]) + off);
        }
        float xg[4];
        #pragma unroll
        for (int g = 0; g < 4; ++g) xg[g] = bf2f(P[g]);

        if (t + 1 < t1) {
            const ush* pn = xp_base + (size_t)(t + 1 - t0) * (1024 * 512);
            #pragma unroll
            for (int g = 0; g < 4; ++g) P[g] = pn[g * 128];
        }

        f32x4 acc[4];
        #pragma unroll
        for (int g = 0; g < 4; ++g) acc[g] = (f32x4){0.f, 0.f, 0.f, 0.f};
        #pragma unroll
        for (int kf = 0; kf < 4; ++kf)
            #pragma unroll
            for (int g = 0; g < 4; ++g)
                acc[g] = __builtin_amdgcn_mfma_f32_16x16x32_bf16(
                    afr[kf], whf[g][kf], acc[g], 0, 0, 0);

        // redistribute C frags: lane l takes reg q=lq from lane l16 -> full-wave gates
        float pre[4];
        #pragma unroll
        for (int g = 0; g < 4; ++g) {
            float a0 = __shfl(acc[g][0], l16);
            float a1 = __shfl(acc[g][1], l16);
            float a2 = __shfl(acc[g][2], l16);
            float a3 = __shfl(acc[g][3], l16);
            float v = (lq == 0) ? a0 : (lq == 1) ? a1 : (lq == 2) ? a2 : a3;
            pre[g] = v + xg[g];
        }
        float fg = sigm_f(pre[0]);
        float ig = sigm_f(pre[1]);
        float gg = tanh_f(pre[2]);
        float og = sigm_f(pre[3]);
        float cn = fg * c1 + ig * gg;
        c1 = cn;
        float hv = og * tanh_f(cn);
        out0[(size_t)(b0 + lq) * (270 * 128) + (size_t)t * 128 + jcol] = hv;
        {
            int off = ((lq * 128 + jcol) * 2) ^ ((lq & 7) << 4);
            *(ush*)((char*)(&h_lds[cur ^ 1][0]) + off) = f2bf(hv);
        }
        __syncthreads();
        cur ^= 1;
    }
    c_state[(size_t)(b0 + lq) * 128 + jcol] = c1;
}

// ---------------- logits + softmax ----------------
__global__ __launch_bounds__(256) void logits_softmax(
    const float* __restrict__ h_all, const float* __restrict__ Wy,
    const float* __restrict__ by, float* __restrict__ out1)
{
    __shared__ float h_s[64 * 132];
    __shared__ float wy_s[3 * 128];
    const int tid = threadIdx.x;
    const size_t p0 = (size_t)blockIdx.x * 64;

    for (int v = tid; v < 2048; v += 256) {
        int q = v >> 5, kk = v & 31;
        f32x4 g = *(const f32x4*)(h_all + p0 * 128 + (size_t)v * 4);
        *(f32x4*)(&h_s[q * 132 + kk * 4]) = g;
    }
    for (int v = tid; v < 384; v += 256) wy_s[v] = Wy[v];
    __syncthreads();

    int q = tid >> 2, cc = tid & 3;
    int ccw = cc < 3 ? cc : 2;
    float L = 0.f;
    #pragma unroll
    for (int k4 = 0; k4 < 32; ++k4) {
        f32x4 hv = *(const f32x4*)(&h_s[q * 132 + k4 * 4]);
        f32x4 wv = *(const f32x4*)(&wy_s[ccw * 128 + k4 * 4]);
        L += hv.x * wv.x + hv.y * wv.y + hv.z * wv.z + hv.w * wv.w;
    }
    L += by[ccw];
    if (cc == 3) L = -1e30f;
    float m = fmaxf(L, __shfl_xor(L, 1));
    m = fmaxf(m, __shfl_xor(m, 2));
    float e = (cc < 3) ? __expf(L - m) : 0.f;
    float s = e + __shfl_xor(e, 1);
    s = s + __shfl_xor(s, 2);
    if (cc < 3) out1[(p0 + q) * 3 + cc] = e / s;
}

// ---------------- host ----------------
extern "C" void kernel_launch(void* const* d_in, const int* in_sizes, int n_in,
                              void* d_out, int out_size, void* d_ws, size_t ws_size,
                              hipStream_t stream) {
    (void)in_sizes; (void)n_in; (void)out_size;
    const float* x   = (const float*)d_in[0];
    const float* Wf  = (const float*)d_in[1];
    const float* Wi  = (const float*)d_in[2];
    const float* Wc  = (const float*)d_in[3];
    const float* Wo  = (const float*)d_in[4];
    const float* Wy  = (const float*)d_in[5];
    const float* bfp = (const float*)d_in[6];
    const float* bip = (const float*)d_in[7];
    const float* bcp = (const float*)d_in[8];
    const float* bop = (const float*)d_in[9];
    const float* byp = (const float*)d_in[10];

    float* out0 = (float*)d_out;                       // [B,T,H]
    float* out1 = out0 + (size_t)1024 * 270 * 128;     // [B,T,3]

    // chunk size: divisors of 270 with Tcur*8 % 3 == 0, largest fitting ws
    // per-step ws: xpc 1 MB + xbf 576 KB; fixed ~1 MB (c_state + packed W)
    long tc = 6;
    {
        const long cand[5] = {90, 54, 30, 18, 6};
        for (int i = 0; i < 5; ++i) {
            size_t need = (size_t)cand[i] * 1638400u + (1u << 20);
            if (need <= ws_size) { tc = cand[i]; break; }
        }
    }
    char* wsb = (char*)d_ws;
    ush* xpc = (ush*)wsb;
    ush* xbf = (ush*)(wsb + (size_t)tc * 1048576u);
    char* fx = wsb + (size_t)tc * 1638400u;
    float* c_state = (float*)fx;                       // 512 KB
    ush* Wxp = (ush*)(fx + 524288);                    // 288 KB
    ush* Whp = (ush*)(fx + 524288 + 294912);           // 128 KB
    float* bpk = (float*)(fx + 524288 + 294912 + 131072);

    pack_w<<<576, 256, 0, stream>>>(Wf, Wi, Wc, Wo, bfp, bip, bcp, bop, Wxp, Whp, bpk);

    for (int t0 = 0; t0 < 270; t0 += (int)tc) {
        int Tcur = (270 - t0) < (int)tc ? (270 - t0) : (int)tc;
        int rows = Tcur * 1024;
        xconv<<<rows / 16, 576, 0, stream>>>(x, xbf, t0, rows);
        dim3 g((rows / 128) / 3, 4);
        xp_gemm<<<g, 512, 0, stream>>>(xbf, Wxp, bpk, xpc);
        lstm_scan<<<256, 512, 0, stream>>>(xpc, Whp, c_state, out0, t0, t0 + Tcur);
    }
    logits_softmax<<<4320, 256, 0, stream>>>(out0, Wy, byp, out1);
}